// Round 4
// baseline (35.772 us; speedup 1.0000x reference)
//
#include <hip/hip_runtime.h>

// VQWeightedAvgPool, fully fused: out[b,d] = sum_l w[b,l] * feat[b, 12, l, d]
// w[b,l] = 1 / (n_seg_b * seg_len_b(l)) for l < len_b, else 0.
// feat (B=16, N=13, L=2048, D=768) f32; lengths (B,) int; vq (B, L, 2) int.
//
// One block per (batch, 32-row L-tile) = 1024 blocks x 192 threads.
// Each block redundantly computes its batch's segment weights from vq
// (16 KB, L2-resident) straight into LDS, then pools its tile and does
// one atomicAdd flush per output float. Out is pre-zeroed by memset.

#define L_SEQ 2048
#define D_DIM 768
#define N_DIM 13
#define LT 32
#define TILES_PER_B (L_SEQ / LT)  // 64
#define BLK 192
#define SCAN_T 128                // threads participating in the scan
#define PER (L_SEQ / SCAN_T)      // 16 positions per scan thread

__global__ __launch_bounds__(BLK) void vq_fused_kernel(
    const float* __restrict__ feat,
    const int* __restrict__ lengths,
    const int* __restrict__ vq,
    float* __restrict__ out) {
  const int tile = blockIdx.x;
  const int b = tile >> 6;               // / TILES_PER_B
  const int t = tile & (TILES_PER_B - 1);
  const int l0 = t * LT;
  const int tid = threadIdx.x;
  const int len = lengths[b];
  if (l0 >= len) return;  // tile fully past len: no barriers touched, safe

  __shared__ int s_seg[L_SEQ];   // inclusive cumsum of boundary (= seg_id+1)
  __shared__ int s_cnt[L_SEQ];   // per-segment valid counts
  __shared__ float s_w[LT];      // this tile's weights
  __shared__ int s_wsum[2];      // per-wave scan totals (2 scan waves)

  const int* vqb = vq + (size_t)b * L_SEQ * 2;

  // ---- phase 1: boundary flags + local/wave scan (threads 0..127) ----
  int flags[PER];
  int v = 0, lsum = 0, wid = 0;
  if (tid < SCAN_T) {
    const int lane = tid & 63;
    wid = tid >> 6;
    int4 q[PER / 2];
    const int4* v4 = (const int4*)vqb;
#pragma unroll
    for (int i = 0; i < PER / 2; ++i) q[i] = v4[(PER / 2) * tid + i];
    int cx[PER], cy[PER];
#pragma unroll
    for (int i = 0; i < PER / 2; ++i) {
      cx[2 * i] = q[i].x; cy[2 * i] = q[i].y;
      cx[2 * i + 1] = q[i].z; cy[2 * i + 1] = q[i].w;
    }
    int px = 0, py = 0;
    if (tid > 0) {
      const int2 pp = *(const int2*)(vqb + 2 * PER * tid - 2);
      px = pp.x; py = pp.y;
    }
    const int base = tid * PER;
#pragma unroll
    for (int i = 0; i < PER; ++i) {
      const int l = base + i;
      int bd = 0;
      if (l < len) {
        if (l == 0) {
          bd = 1;
        } else {
          const int prx = (i == 0) ? px : cx[i - 1];
          const int pry = (i == 0) ? py : cy[i - 1];
          bd = (cx[i] != prx) || (cy[i] != pry);
        }
      }
      lsum += bd;
      flags[i] = lsum;
    }
    v = lsum;
    for (int off = 1; off < 64; off <<= 1) {
      int n = __shfl_up(v, off, 64);
      if (lane >= off) v += n;
    }
    if (lane == 63) s_wsum[wid] = v;
  }
  // zero counts (all 192 threads)
  for (int l = tid; l < L_SEQ; l += BLK) s_cnt[l] = 0;
  __syncthreads();

  // ---- phase 2: write seg ids ----
  const int nseg = s_wsum[0] + s_wsum[1];
  if (tid < SCAN_T) {
    const int excl = (wid ? s_wsum[0] : 0) + (v - lsum);
    const int base = tid * PER;
#pragma unroll
    for (int i = 0; i < PER; ++i) s_seg[base + i] = excl + flags[i];
  }
  __syncthreads();

  // ---- phase 3: segment counts (valid positions only) ----
  for (int l = tid; l < L_SEQ; l += BLK)
    if (l < len) atomicAdd(&s_cnt[s_seg[l] - 1], 1);
  __syncthreads();

  // ---- phase 4: this tile's weights ----
  if (tid < LT) {
    const int l = l0 + tid;
    float wv = 0.0f;
    if (l < len) {
      const float denom = fmaxf((float)nseg * (float)s_cnt[s_seg[l] - 1], 1.0f);
      wv = 1.0f / denom;
    }
    s_w[tid] = wv;
  }
  __syncthreads();

  // ---- phase 5: pooling. thread owns float4 at d = 4*tid (768 = 192*4) ----
  float wl[LT];
#pragma unroll
  for (int i = 0; i < LT; ++i) wl[i] = s_w[i];  // LDS broadcast reads

  const float* basep =
      feat + (((size_t)b * N_DIM + (N_DIM - 1)) * L_SEQ + l0) * D_DIM + tid * 4;
  float4 acc = make_float4(0.f, 0.f, 0.f, 0.f);
#pragma unroll
  for (int i = 0; i < LT; ++i) {
    const float4 vx = *(const float4*)(basep + (size_t)i * D_DIM);
    acc.x += wl[i] * vx.x;
    acc.y += wl[i] * vx.y;
    acc.z += wl[i] * vx.z;
    acc.w += wl[i] * vx.w;
  }

  float* o = out + (size_t)b * D_DIM + tid * 4;
  atomicAdd(o + 0, acc.x);
  atomicAdd(o + 1, acc.y);
  atomicAdd(o + 2, acc.z);
  atomicAdd(o + 3, acc.w);
}

extern "C" void kernel_launch(void* const* d_in, const int* in_sizes, int n_in,
                              void* d_out, int out_size, void* d_ws, size_t ws_size,
                              hipStream_t stream) {
  const float* feat = (const float*)d_in[0];
  const int* lengths = (const int*)d_in[1];
  const int* vq = (const int*)d_in[2];
  float* out = (float*)d_out;

  const int B = in_sizes[1];  // 16

  hipMemsetAsync(d_out, 0, (size_t)out_size * sizeof(float), stream);
  vq_fused_kernel<<<B * TILES_PER_B, BLK, 0, stream>>>(feat, lengths, vq, out);
}

// Round 5
// 30.110 us; speedup vs baseline: 1.1881x; 1.1881x over previous
//
#include <hip/hip_runtime.h>

// VQWeightedAvgPool: out[b,d] = sum_l w[b,l] * feat[b, N-1, l, d]
// w[b,l] = 1 / (n_seg_b * seg_len_b(l)) for l < len_b, else 0.
// feat (B=16, N=13, L=2048, D=768) f32; lengths (B,) int; vq (B, L, 2) int.

#define L_SEQ 2048
#define D_DIM 768
#define N_DIM 13
#define BLK_A 1024
#define PER_A 2                  // 2048 / 1024
#define NWAVE_A (BLK_A / 64)     // 16
#define LT 32                    // L-rows per pooling tile
#define MAX_TILES (L_SEQ / LT)   // 64
#define SUBS 48                  // pooling blocks per batch

// ---------------- Kernel A: per-batch segment weights (+ zero out) ----------
// 16 blocks x 1024 threads. Thread t owns l in [2t, 2t+2).
__global__ __launch_bounds__(BLK_A) void vq_weights_kernel(
    const int* __restrict__ lengths,
    const int* __restrict__ vq,
    float* __restrict__ w,
    float* __restrict__ out) {
  __shared__ int s_seg[L_SEQ];     // inclusive cumsum of boundary (= seg_id+1)
  __shared__ int s_cnt[L_SEQ];     // per-segment valid counts
  __shared__ int s_wsum[NWAVE_A];  // per-wave scan totals

  const int b = blockIdx.x;
  const int tid = threadIdx.x;
  const int lane = tid & 63;
  const int wid = tid >> 6;
  const int len = lengths[b];
  const int* vqb = vq + (size_t)b * L_SEQ * 2;

  // zero this batch's output slice (replaces hipMemsetAsync launch)
  if (tid < D_DIM) out[(size_t)b * D_DIM + tid] = 0.0f;

  // one coalesced int4 per thread = pairs for l = 2t, 2t+1
  const int4 q = ((const int4*)vqb)[tid];
  int px = 0, py = 0;
  if (tid > 0) {
    const int2 pp = *(const int2*)(vqb + 4 * tid - 2);  // pair of l = 2t-1
    px = pp.x; py = pp.y;
  }

  // boundary flags + local inclusive prefix (2 positions)
  int f0 = 0, f1 = 0;
  {
    const int l0 = 2 * tid, l1 = 2 * tid + 1;
    int b0 = 0, b1 = 0;
    if (l0 < len) b0 = (l0 == 0) ? 1 : ((q.x != px) || (q.y != py));
    if (l1 < len) b1 = (q.z != q.x) || (q.w != q.y);
    f0 = b0;
    f1 = b0 + b1;
  }
  const int lsum = f1;

  // wave-level inclusive scan of per-thread totals
  int v = lsum;
  for (int off = 1; off < 64; off <<= 1) {
    int n = __shfl_up(v, off, 64);
    if (lane >= off) v += n;
  }
  if (lane == 63) s_wsum[wid] = v;
  // zero counts while scan totals settle
  s_cnt[tid] = 0;
  s_cnt[tid + BLK_A] = 0;
  __syncthreads();

  int woff = 0, nseg = 0;
#pragma unroll
  for (int i = 0; i < NWAVE_A; ++i) {
    const int s = s_wsum[i];
    if (i < wid) woff += s;
    nseg += s;
  }
  const int excl = woff + (v - lsum);
  s_seg[2 * tid] = excl + f0;
  s_seg[2 * tid + 1] = excl + f1;
  __syncthreads();

  // segment counts (valid positions only)
  if (2 * tid < len) atomicAdd(&s_cnt[s_seg[2 * tid] - 1], 1);
  if (2 * tid + 1 < len) atomicAdd(&s_cnt[s_seg[2 * tid + 1] - 1], 1);
  __syncthreads();

  const float nsegf = (float)nseg;
  float w0 = 0.0f, w1 = 0.0f;
  if (2 * tid < len)
    w0 = 1.0f / fmaxf(nsegf * (float)s_cnt[s_seg[2 * tid] - 1], 1.0f);
  if (2 * tid + 1 < len)
    w1 = 1.0f / fmaxf(nsegf * (float)s_cnt[s_seg[2 * tid + 1] - 1], 1.0f);
  *(float2*)(w + (size_t)b * L_SEQ + 2 * tid) = make_float2(w0, w1);
}

// ---------------- Kernel B: weighted pooling over L ----------------
// 768 blocks: (b = blk/48, sub = blk%48). Block handles valid tiles
// t = sub, sub+48, ... < nt; accumulates in regs; ONE atomic flush.
// 192 threads: thread owns float4 at d = 4*tid (768 = 192*4).
__global__ __launch_bounds__(192) void vq_pool_kernel(
    const float* __restrict__ feat,
    const float* __restrict__ lengths_f,  // actually int*
    const float* __restrict__ w,
    float* __restrict__ out) {
  const int b = blockIdx.x / SUBS;
  const int sub = blockIdx.x - b * SUBS;
  const int tid = threadIdx.x;
  const int len = ((const int*)lengths_f)[b];
  int nt = (len + LT - 1) / LT;
  if (nt > MAX_TILES) nt = MAX_TILES;

  const float* fb = feat + ((size_t)b * N_DIM + (N_DIM - 1)) * L_SEQ * D_DIM;
  const float* wb = w + (size_t)b * L_SEQ;

  float4 acc = make_float4(0.f, 0.f, 0.f, 0.f);
  for (int t = sub; t < nt; t += SUBS) {
    const int l0 = t * LT;
    // tile weights (uniform across lanes); trailing zeros handle len tail
    const float4* wb4 = (const float4*)(wb + l0);
    float wl[LT];
#pragma unroll
    for (int i = 0; i < LT / 4; ++i) {
      const float4 wv = wb4[i];
      wl[4 * i + 0] = wv.x;
      wl[4 * i + 1] = wv.y;
      wl[4 * i + 2] = wv.z;
      wl[4 * i + 3] = wv.w;
    }
    // 32 independent unconditional float4 row loads -> deep MLP
    const float* basep = fb + (size_t)l0 * D_DIM + tid * 4;
#pragma unroll
    for (int i = 0; i < LT; ++i) {
      const float4 vx = *(const float4*)(basep + (size_t)i * D_DIM);
      acc.x += wl[i] * vx.x;
      acc.y += wl[i] * vx.y;
      acc.z += wl[i] * vx.z;
      acc.w += wl[i] * vx.w;
    }
  }

  float* o = out + (size_t)b * D_DIM + tid * 4;
  atomicAdd(o + 0, acc.x);
  atomicAdd(o + 1, acc.y);
  atomicAdd(o + 2, acc.z);
  atomicAdd(o + 3, acc.w);
}

extern "C" void kernel_launch(void* const* d_in, const int* in_sizes, int n_in,
                              void* d_out, int out_size, void* d_ws, size_t ws_size,
                              hipStream_t stream) {
  const float* feat = (const float*)d_in[0];
  const int* lengths = (const int*)d_in[1];
  const int* vq = (const int*)d_in[2];
  float* out = (float*)d_out;
  float* w = (float*)d_ws;  // B*L floats = 128 KiB

  const int B = in_sizes[1];  // 16

  vq_weights_kernel<<<B, BLK_A, 0, stream>>>(lengths, vq, w, out);
  vq_pool_kernel<<<B * SUBS, 192, 0, stream>>>(feat, (const float*)lengths, w, out);
}